// Round 10
// baseline (682.588 us; speedup 1.0000x reference)
//
#include <hip/hip_runtime.h>
#include <hip/hip_bf16.h>
#include <math.h>

// Problem constants (fixed by setup_inputs)
#define BB 4
#define NN 16384
#define SS 4096
#define D1 128
#define D2 256
#define C1 256   // mlp[0]
#define C2 128   // mlp[1]
#define MTOT (BB*NN)   // 65536

// knn decomposition (R6/R9 measured optimum: 172 us, VALUBusy ~107%)
#define QPT 2              // queries per thread
#define SCH 512            // candidates per chunk (8KB LDS)
#define NCH (SS/SCH)       // 8 chunks

typedef _Float16 f16x8 __attribute__((ext_vector_type(8)));
typedef float f32x4  __attribute__((ext_vector_type(4)));

// ---------------------------------------------------------------------------
// Pack xyz2 into float4 {x, y, z, ||p||^2} (exact reference association).
// ---------------------------------------------------------------------------
__global__ __launch_bounds__(256) void pack_kernel(
    const float* __restrict__ xyz2, float4* __restrict__ packed)
{
#pragma clang fp contract(off)
    int s = blockIdx.x * 256 + threadIdx.x;
    float px = xyz2[s*3+0], py = xyz2[s*3+1], pz = xyz2[s*3+2];
    float pp = (px*px + py*py) + pz*pz;
    packed[s] = make_float4(px, py, pz, pp);
}

// ---------------------------------------------------------------------------
// Convert W1, W2 to fp16 (RNE) once.
// ---------------------------------------------------------------------------
__global__ __launch_bounds__(256) void wcvt_kernel(
    const float* __restrict__ W1, const float* __restrict__ W2,
    _Float16* __restrict__ W1c, _Float16* __restrict__ W2c)
{
    int i = blockIdx.x * 256 + threadIdx.x;
    if (i < C1 * (D1 + D2)) W1c[i] = (_Float16)W1[i];
    if (i < C2 * C1)        W2c[i] = (_Float16)W2[i];
}

// ---------------------------------------------------------------------------
// 3-NN pass 1 (FROZEN since R6: 172us, VALU-saturated):
// exact fp32 distances (contract off, reference association), min/med3
// distance chain + cndmask index chain, strict '<' (stable like lax.top_k).
// HARD CONSTRAINT (R7): selection is discontinuous in gathered features ->
// never approximate the distance or the comparison.
// ---------------------------------------------------------------------------
__global__ __launch_bounds__(256) void knn3_partial_kernel(
    const float* __restrict__ xyz1, const float4* __restrict__ packed,
    float* __restrict__ pdist, int* __restrict__ pidx)
{
#pragma clang fp contract(off)
    __shared__ float4 pk[SCH];                       // 8 KB

    const int qblocks = NN / (256 * QPT);            // 32
    const int b  = blockIdx.x / (qblocks * NCH);
    const int r  = blockIdx.x % (qblocks * NCH);
    const int qc = r / NCH;
    const int sc = r % NCH;

    const float4* src = packed + (size_t)b * SS + sc * SCH;
    for (int i = threadIdx.x; i < SCH; i += 256) pk[i] = src[i];
    __syncthreads();

    float qx[QPT], qy[QPT], qz[QPT], qq[QPT];
    float e0[QPT], e1[QPT], e2[QPT];
    int   j0[QPT], j1[QPT], j2[QPT];
#pragma unroll
    for (int q = 0; q < QPT; ++q) {
        int n = qc * (256 * QPT) + q * 256 + threadIdx.x;
        size_t m = (size_t)b * NN + n;
        qx[q] = xyz1[m*3+0]; qy[q] = xyz1[m*3+1]; qz[q] = xyz1[m*3+2];
        qq[q] = (qx[q]*qx[q] + qy[q]*qy[q]) + qz[q]*qz[q];
        e0[q] = 3.4e38f; e1[q] = 3.4e38f; e2[q] = 3.4e38f;
        j0[q] = 0; j1[q] = 0; j2[q] = 0;
    }

#pragma unroll 4
    for (int s = 0; s < SCH; ++s) {
        float4 p = pk[s];
#pragma unroll
        for (int q = 0; q < QPT; ++q) {
            float cr = (qx[q]*p.x + qy[q]*p.y) + qz[q]*p.z;
            float d = (qq[q] - 2.0f*cr) + p.w;
            d = fmaxf(d, 0.0f);
            bool c0 = d < e0[q], c1 = d < e1[q], c2 = d < e2[q];
            j2[q] = c1 ? j1[q] : (c2 ? s : j2[q]);
            j1[q] = c0 ? j0[q] : (c1 ? s : j1[q]);
            j0[q] = c0 ? s : j0[q];
            e2[q] = __builtin_amdgcn_fmed3f(e1[q], d, e2[q]);
            e1[q] = __builtin_amdgcn_fmed3f(e0[q], d, e1[q]);
            e0[q] = fminf(e0[q], d);
        }
    }

#pragma unroll
    for (int q = 0; q < QPT; ++q) {
        int n = qc * (256 * QPT) + q * 256 + threadIdx.x;
        size_t m = (size_t)b * NN + n;
        size_t base = (m * NCH + sc) * 3;
        pdist[base+0] = e0[q]; pdist[base+1] = e1[q]; pdist[base+2] = e2[q];
        pidx [base+0] = sc*SCH + j0[q];
        pidx [base+1] = sc*SCH + j1[q];
        pidx [base+2] = sc*SCH + j2[q];
    }
}

// ---------------------------------------------------------------------------
// 3-NN pass 2: merge chunk triples (ascending chunk order, strict '<').
// ---------------------------------------------------------------------------
__global__ __launch_bounds__(256) void knn3_merge_kernel(
    const float* __restrict__ pdist, const int* __restrict__ pidx,
    int* __restrict__ idx_out, float* __restrict__ w_out)
{
#pragma clang fp contract(off)
    int m = blockIdx.x * 256 + threadIdx.x;
    int b = m / NN;
    size_t base = (size_t)m * NCH * 3;
    float d0 = pdist[base+0], d1 = pdist[base+1], d2 = pdist[base+2];
    int   i0 = pidx [base+0], i1 = pidx [base+1], i2 = pidx [base+2];
#pragma unroll
    for (int c = 1; c < NCH; ++c) {
#pragma unroll
        for (int j = 0; j < 3; ++j) {
            float d = pdist[base + c*3 + j];
            int   s = pidx [base + c*3 + j];
            bool c0 = d < d0, c1 = d < d1, c2 = d < d2;
            d2 = c1 ? d1 : (c2 ? d : d2);  i2 = c1 ? i1 : (c2 ? s : i2);
            d1 = c0 ? d0 : (c1 ? d : d1);  i1 = c0 ? i0 : (c1 ? s : i1);
            d0 = c0 ? d : d0;              i0 = c0 ? s : i0;
        }
    }
    float r0 = 1.0f / (d0 + 1e-8f);
    float r1 = 1.0f / (d1 + 1e-8f);
    float r2 = 1.0f / (d2 + 1e-8f);
    float inv = 1.0f / ((r0 + r1) + r2);
    idx_out[m*3+0] = b * SS + i0;
    idx_out[m*3+1] = b * SS + i1;
    idx_out[m*3+2] = b * SS + i2;
    w_out[m*3+0] = r0 * inv;
    w_out[m*3+1] = r1 * inv;
    w_out[m*3+2] = r2 * inv;
}

// ---------------------------------------------------------------------------
// Strip GEMM (one barrier per block): C[M x N] = op(A[M x K]) @ W[N x K]^T.
// W tile (NT=64 rows x K) staged into LDS ONCE; each wave then streams its
// 16-row A strip global->registers (A has no reuse -> no LDS round-trip) and
// fires the full NI x KF MFMA burst with B frags from LDS. No k-loop, no
// per-iter barriers (R5-R9: those were the invariant ~300us cost).
// LDS row pad +8 f16 -> 2-way bank aliasing only (free, m136).
// Accumulation order (kf ascending per ni) is bit-identical to R9.
// ---------------------------------------------------------------------------
template<int K, typename AT, typename OT, bool BN_A, bool FUSE_INTERP, bool FUSE_STATS>
__global__ __launch_bounds__(256) void gemm_strip_kernel(
    const AT* __restrict__ A, int lda,
    const _Float16* __restrict__ W, int ldw,
    OT* __restrict__ Cc, int ldc,
    const float* __restrict__ bias,
    const float* __restrict__ scaleA, const float* __restrict__ shiftA,
    const _Float16* __restrict__ P2, const int* __restrict__ idx3, const float* __restrict__ w3,
    float* __restrict__ sumO, float* __restrict__ sqO)
{
    constexpr int NT = 64;              // N-tile per block
    constexpr int KF = K / 32;          // k-frags per MFMA row (4 or 8)
    constexpr int NI = NT / 16;         // n-tiles (4)
    constexpr int LROW = K + 8;         // LDS row stride in f16 (16B pad)
    __shared__ _Float16 Wsh[NT * LROW]; // 17.4 KB (K=128) / 33.8 KB (K=256)

    const int tid = threadIdx.x;
    const int m0 = blockIdx.x * 64;
    const int n0 = blockIdx.y * NT;
    const int wave = tid >> 6, lane = tid & 63;
    const int ln = lane & 15, q4 = lane >> 4;

    // ---- stage W once (coalesced 16B chunks) ----
    constexpr int CPR = K / 8;                       // chunks per W row
    constexpr int CPT = (NT * CPR) / 256;            // chunks per thread
#pragma unroll
    for (int i = 0; i < CPT; ++i) {
        int c = i * 256 + tid;
        int row = c / CPR, off = (c % CPR) * 8;
        *(f16x8*)&Wsh[row * LROW + off] =
            *(const f16x8*)(W + (size_t)(n0 + row) * ldw + off);
    }

    // ---- A strip: global -> registers (issued before barrier; overlaps) ----
    const int arow = m0 + wave * 16 + ln;
    f16x8 afr[KF];
#pragma unroll
    for (int kf = 0; kf < KF; ++kf) {
        const int kb = kf * 32 + q4 * 8;
        if constexpr (__is_same(AT, float)) {
            float av[8];
            const float* ap = A + (size_t)arow * lda + kb;
            *(float4*)&av[0] = *(const float4*)ap;
            *(float4*)&av[4] = *(const float4*)(ap + 4);
            f16x8 h;
#pragma unroll
            for (int i = 0; i < 8; ++i) h[i] = (_Float16)av[i];
            afr[kf] = h;
        } else {
            f16x8 h = *(const f16x8*)(A + (size_t)arow * lda + kb);
            if (BN_A) {
                float4 sc0 = *(const float4*)(scaleA + kb);
                float4 sc1 = *(const float4*)(scaleA + kb + 4);
                float4 sh0 = *(const float4*)(shiftA + kb);
                float4 sh1 = *(const float4*)(shiftA + kb + 4);
                float av[8];
#pragma unroll
                for (int i = 0; i < 8; ++i) av[i] = (float)h[i];
                av[0] = fmaxf(av[0]*sc0.x + sh0.x, 0.0f);
                av[1] = fmaxf(av[1]*sc0.y + sh0.y, 0.0f);
                av[2] = fmaxf(av[2]*sc0.z + sh0.z, 0.0f);
                av[3] = fmaxf(av[3]*sc0.w + sh0.w, 0.0f);
                av[4] = fmaxf(av[4]*sc1.x + sh1.x, 0.0f);
                av[5] = fmaxf(av[5]*sc1.y + sh1.y, 0.0f);
                av[6] = fmaxf(av[6]*sc1.z + sh1.z, 0.0f);
                av[7] = fmaxf(av[7]*sc1.w + sh1.w, 0.0f);
#pragma unroll
                for (int i = 0; i < 8; ++i) h[i] = (_Float16)av[i];
            }
            afr[kf] = h;
        }
    }

    __syncthreads();    // the ONLY barrier: W staged

    // ---- full MFMA burst, B frags from LDS ----
    f32x4 acc[NI] = {};
#pragma unroll
    for (int ni = 0; ni < NI; ++ni) {
        const int brow = ni * 16 + ln;
#pragma unroll
        for (int kf = 0; kf < KF; ++kf) {
            f16x8 bf = *(const f16x8*)&Wsh[brow * LROW + kf * 32 + q4 * 8];
            acc[ni] = __builtin_amdgcn_mfma_f32_16x16x32_f16(afr[kf], bf, acc[ni], 0, 0, 0);
        }
    }

    // ---- epilogue ----  C/D layout: col = ln, row = q4*4 + r  (m89/m91)
    const int row_base = m0 + wave * 16 + q4 * 4;
    if (FUSE_INTERP) {
#pragma unroll
        for (int r = 0; r < 4; ++r) {
            int row_g = row_base + r;
            const int*   ip = idx3 + (size_t)row_g * 3;
            const float* wp = w3   + (size_t)row_g * 3;
            int   ia = ip[0], ib = ip[1], ic = ip[2];
            float wa = wp[0], wb = wp[1], wc = wp[2];
#pragma unroll
            for (int ni = 0; ni < NI; ++ni) {
                int col = n0 + ni * 16 + ln;
                acc[ni][r] += wa * (float)P2[(size_t)ia * C1 + col]
                            + wb * (float)P2[(size_t)ib * C1 + col]
                            + wc * (float)P2[(size_t)ic * C1 + col];
            }
        }
    }

#pragma unroll
    for (int ni = 0; ni < NI; ++ni) {
        int col = n0 + ni * 16 + ln;
        float vb = bias ? bias[col] : 0.0f;
        float s = 0.0f, s2 = 0.0f;
#pragma unroll
        for (int r = 0; r < 4; ++r) {
            float v = acc[ni][r] + vb;
            Cc[(size_t)(row_base + r) * ldc + col] = (OT)v;
            s += v; s2 += v * v;
        }
        if (FUSE_STATS) {
            s  += __shfl_xor(s, 16);  s  += __shfl_xor(s, 32);
            s2 += __shfl_xor(s2, 16); s2 += __shfl_xor(s2, 32);
            if (q4 == 0) {
                atomicAdd(&sumO[col], s);
                atomicAdd(&sqO[col], s2);
            }
        }
    }
}

// ---------------------------------------------------------------------------
__global__ void finalize_kernel(
    const float* __restrict__ sum, const float* __restrict__ sumsq,
    const float* __restrict__ g, const float* __restrict__ beta,
    int M, int C, float* __restrict__ scale, float* __restrict__ shift)
{
    int c = threadIdx.x;
    if (c >= C) return;
    float invM = 1.0f / (float)M;
    float mean = sum[c] * invM;
    float var = fmaxf(sumsq[c] * invM - mean * mean, 0.0f);
    float rstd = 1.0f / sqrtf(var + 1e-5f);
    float sc = g[c] * rstd;
    scale[c] = sc;
    shift[c] = beta[c] - mean * sc;
}

__global__ __launch_bounds__(256) void bnrelu_kernel(
    float* __restrict__ X, int total, int C,
    const float* __restrict__ scale, const float* __restrict__ shift)
{
    int i = blockIdx.x * 256 + threadIdx.x;
    if (i >= total) return;
    int c = i & (C - 1);
    X[i] = fmaxf(X[i] * scale[c] + shift[c], 0.0f);
}

// ---------------------------------------------------------------------------
extern "C" void kernel_launch(void* const* d_in, const int* in_sizes, int n_in,
                              void* d_out, int out_size, void* d_ws, size_t ws_size,
                              hipStream_t stream) {
    const float* xyz1    = (const float*)d_in[0];
    const float* xyz2    = (const float*)d_in[1];
    const float* points1 = (const float*)d_in[2];
    const float* points2 = (const float*)d_in[3];
    const float* W1      = (const float*)d_in[4];
    const float* b1      = (const float*)d_in[5];
    const float* g1      = (const float*)d_in[6];
    const float* beta1   = (const float*)d_in[7];
    const float* W2      = (const float*)d_in[8];
    const float* b2      = (const float*)d_in[9];
    const float* g2      = (const float*)d_in[10];
    const float* beta2   = (const float*)d_in[11];
    float* out = (float*)d_out;

    // ws layout (byte offsets, 16B-aligned)
    char* ws = (char*)d_ws;
    size_t off = 0;
    int*   idx = (int*)(ws + off);            off += (size_t)MTOT*3*4;
    float* w   = (float*)(ws + off);          off += (size_t)MTOT*3*4;
    _Float16* P2h = (_Float16*)(ws + off);    off += (size_t)BB*SS*C1*2;    // 8 MB
    _Float16* y1h = (_Float16*)(ws + off);    off += (size_t)MTOT*C1*2;     // 32 MB
    float* stats = (float*)(ws + off);        off += 2048*4;
    float* sum1 = stats;            // 256
    float* sq1  = stats + 256;      // 256
    float* sum2 = stats + 512;      // 128
    float* sq2  = stats + 640;      // 128
    float* scale1 = stats + 768;    // 256
    float* shift1 = stats + 1024;   // 256
    float* scale2 = stats + 1280;   // 128
    float* shift2 = stats + 1408;   // 128
    float4* packed = (float4*)(ws + off);     off += (size_t)BB*SS*16;      // 1 MB
    _Float16* W1c = (_Float16*)(ws + off);    off += (size_t)C1*(D1+D2)*2;
    _Float16* W2c = (_Float16*)(ws + off);    off += (size_t)C2*C1*2;
    // knn partials (12.6 MB) alias the y1h region (y1h written later in stream order)
    float* pdist = (float*)y1h;                              // MTOT*NCH*3 floats
    int*   pidx  = (int*)((char*)y1h + (size_t)MTOT*NCH*3*4);// MTOT*NCH*3 ints

    hipMemsetAsync(stats, 0, 768 * sizeof(float), stream);

    pack_kernel<<<(BB*SS)/256, 256, 0, stream>>>(xyz2, packed);
    wcvt_kernel<<<(C1*(D1+D2))/256, 256, 0, stream>>>(W1, W2, W1c, W2c);

    knn3_partial_kernel<<<BB * (NN/(256*QPT)) * NCH, 256, 0, stream>>>(
        xyz1, packed, pdist, pidx);
    knn3_merge_kernel<<<MTOT/256, 256, 0, stream>>>(pdist, pidx, idx, w);

    // P2 = points2 @ W1[:,128:]^T   [B*S x 256], K=256, f16 out
    gemm_strip_kernel<256, float, _Float16, false, false, false>
        <<<dim3((BB*SS)/64, C1/64), 256, 0, stream>>>(
        points2, D2, W1c + D1, D1 + D2, P2h, C1,
        nullptr, nullptr, nullptr, nullptr, nullptr, nullptr, nullptr, nullptr);

    // y1 = points1 @ W1[:,:128]^T + b1 + interp;  f16 out; fused BN1 stats (fp32)
    gemm_strip_kernel<128, float, _Float16, false, true, true>
        <<<dim3(MTOT/64, C1/64), 256, 0, stream>>>(
        points1, D1, W1c, D1 + D2, y1h, C1,
        b1, nullptr, nullptr, P2h, idx, w, sum1, sq1);

    finalize_kernel<<<1, 256, 0, stream>>>(sum1, sq1, g1, beta1, MTOT, C1, scale1, shift1);

    // out = relu(bn1(y1)) @ W2^T + b2;  fp32 out; fused BN2 stats
    gemm_strip_kernel<256, _Float16, float, true, false, true>
        <<<dim3(MTOT/64, C2/64), 256, 0, stream>>>(
        y1h, C1, W2c, C1, out, C2,
        b2, scale1, shift1, nullptr, nullptr, nullptr, sum2, sq2);

    finalize_kernel<<<1, 128, 0, stream>>>(sum2, sq2, g2, beta2, MTOT, C2, scale2, shift2);
    bnrelu_kernel<<<(MTOT*C2)/256, 256, 0, stream>>>(out, MTOT*C2, C2, scale2, shift2);
}